// Round 7
// baseline (357.573 us; speedup 1.0000x reference)
//
#include <hip/hip_runtime.h>
#include <cstdint>
#include <cstddef>

// Problem constants
#define TD 512     // d_model
#define TF 2048    // d_ff
#define NE 8       // experts
#define NT 8192    // tokens (B*S)
#define CAP 17408  // padded assignment slots: 16384 + 8*128

using u16 = unsigned short;
using u32 = unsigned int;

typedef __attribute__((ext_vector_type(8))) __bf16 bf16x8;
typedef __attribute__((ext_vector_type(4))) float f32x4;

__device__ __forceinline__ u16 f2bf(float f) {
  u32 u = __float_as_uint(f);
  u32 r = (u + 0x7fffu + ((u >> 16) & 1u)) >> 16;
  return (u16)r;
}

__device__ __forceinline__ float bf2f(u16 b) {
  return __uint_as_float((u32)b << 16);
}

// async global->LDS, 16B per lane; LDS dest = wave-uniform base + lane*16
__device__ __forceinline__ void load_lds16(const void* g, void* l) {
  __builtin_amdgcn_global_load_lds(
      (const __attribute__((address_space(1))) void*)g,
      (__attribute__((address_space(3))) void*)l, 16, 0, 0);
}

// ---------------- 64x64 transpose+convert tile (256 threads) ----------------
__device__ __forceinline__ void transpose64(const float* __restrict__ ib,
                                            u16* __restrict__ ob, int R, int C,
                                            int r0, int c0, u16* tile /*64*68*/) {
  const int tid = threadIdx.x;
  const int l16 = tid & 15;
  const int grp = tid >> 4;   // 0..15
  #pragma unroll
  for (int p = 0; p < 4; p++) {
    int r = p * 16 + grp;
    float4 v = *reinterpret_cast<const float4*>(ib + (size_t)(r0 + r) * C + c0 + l16 * 4);
    u16 o[4] = {f2bf(v.x), f2bf(v.y), f2bf(v.z), f2bf(v.w)};
    *reinterpret_cast<uint2*>(&tile[r * 68 + l16 * 4]) = *reinterpret_cast<uint2*>(o);
  }
  __syncthreads();
  #pragma unroll
  for (int p = 0; p < 4; p++) {
    int c = p * 16 + grp;
    int rr = l16 * 4;
    u16 o[4] = {tile[(rr + 0) * 68 + c], tile[(rr + 1) * 68 + c],
                tile[(rr + 2) * 68 + c], tile[(rr + 3) * 68 + c]};
    *reinterpret_cast<uint2*>(ob + (size_t)(c0 + c) * R + r0 + rr) = *reinterpret_cast<uint2*>(o);
  }
}

// ---------------- prep: router (+x->bf16) fused with both weight transposes ----------------
__global__ void prep_kernel(const float* __restrict__ x, const float* __restrict__ rw,
                            const float* __restrict__ rb, int2* __restrict__ tokE,
                            float2* __restrict__ tokG, u16* __restrict__ xb,
                            const float* __restrict__ w1, u16* __restrict__ w1t,
                            const float* __restrict__ w2, u16* __restrict__ w2t,
                            int* __restrict__ ghist) {
  __shared__ u16 tile[64 * 68];
  int b = blockIdx.x;
  if (b < NT / 4) {
    if (b == 0 && threadIdx.x < 16) ghist[threadIdx.x] = 0;
    int wv = threadIdx.x >> 6;
    int lane = threadIdx.x & 63;
    int t = b * 4 + wv;
    const float* xr = x + (size_t)t * TD;
    float4 a0 = *reinterpret_cast<const float4*>(xr + lane * 4);
    float4 a1 = *reinterpret_cast<const float4*>(xr + 256 + lane * 4);
    {
      u16 o[8];
      o[0] = f2bf(a0.x); o[1] = f2bf(a0.y); o[2] = f2bf(a0.z); o[3] = f2bf(a0.w);
      o[4] = f2bf(a1.x); o[5] = f2bf(a1.y); o[6] = f2bf(a1.z); o[7] = f2bf(a1.w);
      u16* xo = xb + (size_t)t * TD;
      *reinterpret_cast<uint2*>(xo + lane * 4) = *reinterpret_cast<uint2*>(o);
      *reinterpret_cast<uint2*>(xo + 256 + lane * 4) = *reinterpret_cast<uint2*>(o + 4);
    }
    float p[NE];
    #pragma unroll
    for (int e = 0; e < NE; e++) p[e] = 0.f;
    float av[8] = {a0.x, a0.y, a0.z, a0.w, a1.x, a1.y, a1.z, a1.w};
    #pragma unroll
    for (int j = 0; j < 8; j++) {
      int d = (j < 4) ? (lane * 4 + j) : (256 + lane * 4 + j - 4);
      const float* r = rw + (size_t)d * NE;
      #pragma unroll
      for (int e = 0; e < NE; e++) p[e] += av[j] * r[e];
    }
    #pragma unroll
    for (int off = 32; off >= 1; off >>= 1) {
      #pragma unroll
      for (int e = 0; e < NE; e++) p[e] += __shfl_xor(p[e], off);
    }
    if (lane == 0) {
      float l[NE];
      #pragma unroll
      for (int e = 0; e < NE; e++) l[e] = p[e] + rb[e];
      float m = l[0];
      #pragma unroll
      for (int e = 1; e < NE; e++) m = fmaxf(m, l[e]);
      float g[NE];
      #pragma unroll
      for (int e = 0; e < NE; e++) g[e] = __expf(l[e] - m);
      int i0 = 0;
      #pragma unroll
      for (int e = 1; e < NE; e++) if (g[e] > g[i0]) i0 = e;
      int i1 = -1;
      #pragma unroll
      for (int e = 0; e < NE; e++) {
        if (e == i0) continue;
        if (i1 < 0 || g[e] > g[i1]) i1 = e;
      }
      float inv = 1.f / (g[i0] + g[i1]);
      tokE[t] = make_int2(i0, i1);
      tokG[t] = make_float2(g[i0] * inv, g[i1] * inv);
    }
  } else {
    int tb = b - NT / 4;
    int which = tb >> 11;
    int idx = tb & 2047;
    int e = idx >> 8;
    int tl = idx & 255;
    if (which == 0) {
      int rt = tl >> 5, ct = tl & 31;
      transpose64(w1 + (size_t)e * TD * TF, w1t + (size_t)e * TD * TF,
                  TD, TF, rt * 64, ct * 64, tile);
    } else {
      int rt = tl >> 3, ct = tl & 7;
      transpose64(w2 + (size_t)e * TF * TD, w2t + (size_t)e * TF * TD,
                  TF, TD, rt * 64, ct * 64, tile);
    }
  }
}

// ---------------- hist: parallel histogram + last-block offsets/cursors ----------------
__global__ void hist_kernel(const int2* __restrict__ tokE, int* __restrict__ ghist,
                            int* __restrict__ offs, int* __restrict__ cnt,
                            int* __restrict__ cursors) {
  __shared__ int h[NE];
  __shared__ int last;
  if (threadIdx.x < NE) h[threadIdx.x] = 0;
  __syncthreads();
  int t = blockIdx.x * 256 + threadIdx.x;
  int2 e = tokE[t];
  atomicAdd(&h[e.x], 1);
  atomicAdd(&h[e.y], 1);
  __syncthreads();
  if (threadIdx.x < NE) atomicAdd(&ghist[threadIdx.x], h[threadIdx.x]);
  __threadfence();
  if (threadIdx.x == 0) last = (atomicAdd(&ghist[15], 1) == 31);
  __syncthreads();
  if (last) {
    if (threadIdx.x == 0) {
      int tot = 0;
      for (int i = 0; i < NE; i++) {
        int hv = atomicAdd(&ghist[i], 0);
        offs[i] = tot;
        cnt[i] = hv;
        tot += (hv + 127) & ~127;
      }
      offs[NE] = tot;
    }
    if (threadIdx.x < NE) cursors[threadIdx.x * 16] = 0;
  }
}

// ---------------- scatter assignments (wave-aggregated atomics) ----------------
__global__ void scatter_kernel(const int2* __restrict__ tokE,
                               const int* __restrict__ offs, int* __restrict__ cursors,
                               int* __restrict__ tok, int* __restrict__ slotOf) {
  int t = blockIdx.x * 256 + threadIdx.x;
  int lane = threadIdx.x & 63;
  int2 e = tokE[t];
  #pragma unroll
  for (int k = 0; k < 2; k++) {
    int ek = k ? e.y : e.x;
    #pragma unroll
    for (int ex = 0; ex < NE; ex++) {
      unsigned long long mask = __ballot(ek == ex);
      if (ek == ex) {
        int leader = __ffsll(mask) - 1;
        int rank = __popcll(mask & ((1ull << lane) - 1ull));
        int base = 0;
        if (lane == leader) base = atomicAdd(&cursors[ex * 16], __popcll(mask));
        base = __shfl(base, leader);
        int s = offs[ex] + base + rank;
        tok[s] = t;
        slotOf[t * 2 + k] = s;
      }
    }
  }
}

// ---------------- GEMM1  H = relu(x_gather @ W1 + b1), bf16 out ----------------
// A (gathered x) staged in LDS (XOR-swizzled, async); B (w1t) read directly from
// global into registers (k-contiguous dwordx4, L2/L3-hot, shared across s-blocks),
// double-buffered one stage ahead. Halves LDS read traffic (the measured ceiling).
__global__ __launch_bounds__(256, 2) void gemm1_kernel(
    const u16* __restrict__ xb, const u16* __restrict__ w1t,
    const float* __restrict__ b1, const int* __restrict__ tok,
    const int* __restrict__ offs, const int* __restrict__ cnt,
    u16* __restrict__ H) {
  __shared__ u16 As[128 * 64];
  __shared__ int tokS[128];
  const int tid = threadIdx.x;
  const int s0 = blockIdx.x * 128;
  const int f0 = blockIdx.y * 128;
  int e = 0;
  #pragma unroll
  for (int i = 1; i <= 7; i++)
    if (s0 >= offs[i]) e = i;
  const int vend = offs[e] + cnt[e];
  if (tid < 128) {
    int s = s0 + tid;
    tokS[tid] = (s < vend) ? tok[s] : 0;
  }
  __syncthreads();

  const int lane = tid & 63;
  const int wv = tid >> 6;
  const int srow = lane >> 3;
  const int scol = (((lane & 7) ^ srow) & 7) * 8;   // swizzled 16B col group
  const int wm = (wv >> 1) * 64;
  const int wn = (wv & 1) * 64;
  const int mrow = lane & 15;
  const int quad = lane >> 4;
  const int rq = mrow & 7;
  const int koff = quad * 8;

  // per-lane B row pointers (4 n-rows, k-contiguous)
  const u16* brow[4];
  #pragma unroll
  for (int j = 0; j < 4; j++)
    brow[j] = w1t + ((size_t)e * TF + f0 + wn + j * 16 + mrow) * TD;

  f32x4 zero = {0.f, 0.f, 0.f, 0.f};
  f32x4 acc[4][4];
  #pragma unroll
  for (int i = 0; i < 4; i++)
    #pragma unroll
    for (int j = 0; j < 4; j++) acc[i][j] = zero;

  bf16x8 bc[2][4], bn[2][4];
  #pragma unroll
  for (int ks = 0; ks < 2; ks++)
    #pragma unroll
    for (int j = 0; j < 4; j++)
      bc[ks][j] = *reinterpret_cast<const bf16x8*>(brow[j] + ks * 32 + koff);

  for (int k0 = 0; k0 < TD; k0 += 64) {
    if (k0) __syncthreads();
    #pragma unroll
    for (int p = 0; p < 4; p++) {
      int row = wv * 32 + p * 8 + srow;
      load_lds16(xb + (size_t)tokS[row] * TD + k0 + scol, &As[(wv * 32 + p * 8) * 64]);
    }
    int kn = k0 + 64;
    if (kn < TD) {
      #pragma unroll
      for (int ks = 0; ks < 2; ks++)
        #pragma unroll
        for (int j = 0; j < 4; j++)
          bn[ks][j] = *reinterpret_cast<const bf16x8*>(brow[j] + kn + ks * 32 + koff);
    }
    __syncthreads();
    #pragma unroll
    for (int ks = 0; ks < 2; ks++) {
      bf16x8 a[4];
      #pragma unroll
      for (int i = 0; i < 4; i++)
        a[i] = *reinterpret_cast<const bf16x8*>(
            &As[(wm + i * 16 + mrow) * 64 + ((ks * 4 + quad) ^ rq) * 8]);
      #pragma unroll
      for (int i = 0; i < 4; i++)
        #pragma unroll
        for (int j = 0; j < 4; j++)
          acc[i][j] = __builtin_amdgcn_mfma_f32_16x16x32_bf16(a[i], bc[ks][j], acc[i][j], 0, 0, 0);
    }
    #pragma unroll
    for (int ks = 0; ks < 2; ks++)
      #pragma unroll
      for (int j = 0; j < 4; j++)
        bc[ks][j] = bn[ks][j];
  }

  float bv[4];
  #pragma unroll
  for (int j = 0; j < 4; j++) bv[j] = b1[e * TF + f0 + wn + j * 16 + mrow];
  #pragma unroll
  for (int i = 0; i < 4; i++) {
    #pragma unroll
    for (int r = 0; r < 4; r++) {
      int row = s0 + wm + i * 16 + quad * 4 + r;
      u16* hrow = H + (size_t)row * TF + f0;
      #pragma unroll
      for (int j = 0; j < 4; j++) {
        float v = acc[i][j][r] + bv[j];
        v = v > 0.f ? v : 0.f;
        // non-temporal: H is a 68MB write-once stream; keep it out of L2/L3
        __builtin_nontemporal_store(f2bf(v), &hrow[wn + j * 16 + mrow]);
      }
    }
  }
}

// ---------------- GEMM2  eout[slot] = H[slot] @ W2 + b2 ----------------
// Same structure: A (H) staged in LDS, B (w2t) direct-from-global double-buffered.
__global__ __launch_bounds__(256, 2) void gemm2_kernel(
    const u16* __restrict__ H, const u16* __restrict__ w2t,
    const float* __restrict__ b2, const int* __restrict__ offs,
    u16* __restrict__ eout) {
  __shared__ u16 As[128 * 64];
  const int tid = threadIdx.x;
  const int s0 = blockIdx.x * 128;
  const int d0 = blockIdx.y * 128;
  int e = 0;
  #pragma unroll
  for (int i = 1; i <= 7; i++)
    if (s0 >= offs[i]) e = i;

  const int lane = tid & 63;
  const int wv = tid >> 6;
  const int srow = lane >> 3;
  const int scol = (((lane & 7) ^ srow) & 7) * 8;
  const int wm = (wv >> 1) * 64;
  const int wn = (wv & 1) * 64;
  const int mrow = lane & 15;
  const int quad = lane >> 4;
  const int rq = mrow & 7;
  const int koff = quad * 8;

  const u16* brow[4];
  #pragma unroll
  for (int j = 0; j < 4; j++)
    brow[j] = w2t + ((size_t)e * TD + d0 + wn + j * 16 + mrow) * TF;

  f32x4 zero = {0.f, 0.f, 0.f, 0.f};
  f32x4 acc[4][4];
  #pragma unroll
  for (int i = 0; i < 4; i++)
    #pragma unroll
    for (int j = 0; j < 4; j++) acc[i][j] = zero;

  bf16x8 bc[2][4], bn[2][4];
  #pragma unroll
  for (int ks = 0; ks < 2; ks++)
    #pragma unroll
    for (int j = 0; j < 4; j++)
      bc[ks][j] = *reinterpret_cast<const bf16x8*>(brow[j] + ks * 32 + koff);

  for (int k0 = 0; k0 < TF; k0 += 64) {
    if (k0) __syncthreads();
    #pragma unroll
    for (int p = 0; p < 4; p++) {
      int row = wv * 32 + p * 8 + srow;
      load_lds16(H + (size_t)(s0 + row) * TF + k0 + scol, &As[(wv * 32 + p * 8) * 64]);
    }
    int kn = k0 + 64;
    if (kn < TF) {
      #pragma unroll
      for (int ks = 0; ks < 2; ks++)
        #pragma unroll
        for (int j = 0; j < 4; j++)
          bn[ks][j] = *reinterpret_cast<const bf16x8*>(brow[j] + kn + ks * 32 + koff);
    }
    __syncthreads();
    #pragma unroll
    for (int ks = 0; ks < 2; ks++) {
      bf16x8 a[4];
      #pragma unroll
      for (int i = 0; i < 4; i++)
        a[i] = *reinterpret_cast<const bf16x8*>(
            &As[(wm + i * 16 + mrow) * 64 + ((ks * 4 + quad) ^ rq) * 8]);
      #pragma unroll
      for (int i = 0; i < 4; i++)
        #pragma unroll
        for (int j = 0; j < 4; j++)
          acc[i][j] = __builtin_amdgcn_mfma_f32_16x16x32_bf16(a[i], bc[ks][j], acc[i][j], 0, 0, 0);
    }
    #pragma unroll
    for (int ks = 0; ks < 2; ks++)
      #pragma unroll
      for (int j = 0; j < 4; j++)
        bc[ks][j] = bn[ks][j];
  }

  float bv[4];
  #pragma unroll
  for (int j = 0; j < 4; j++) bv[j] = b2[e * TD + d0 + wn + j * 16 + mrow];
  #pragma unroll
  for (int i = 0; i < 4; i++) {
    #pragma unroll
    for (int r = 0; r < 4; r++) {
      int row = s0 + wm + i * 16 + quad * 4 + r;
      u16* orow = eout + (size_t)row * TD + d0;
      #pragma unroll
      for (int j = 0; j < 4; j++) {
        orow[wn + j * 16 + mrow] = f2bf(acc[i][j][r] + bv[j]);
      }
    }
  }
}

// ---------------- combine: out[t] = gA*eout[sA] + gB*eout[sB] ----------------
__global__ void combine_kernel(const u16* __restrict__ eout, const int* __restrict__ slotOf,
                               const float2* __restrict__ tokG, float* __restrict__ out) {
  int wv = threadIdx.x >> 6;
  int lane = threadIdx.x & 63;
  int t = blockIdx.x * 4 + wv;
  int sA = slotOf[t * 2];
  int sB = slotOf[t * 2 + 1];
  float2 g = tokG[t];
  uint4 ua = *reinterpret_cast<const uint4*>(eout + (size_t)sA * TD + lane * 8);
  uint4 ub = *reinterpret_cast<const uint4*>(eout + (size_t)sB * TD + lane * 8);
  const u16* pa = reinterpret_cast<const u16*>(&ua);
  const u16* pb = reinterpret_cast<const u16*>(&ub);
  float o[8];
  #pragma unroll
  for (int k = 0; k < 8; k++) o[k] = g.x * bf2f(pa[k]) + g.y * bf2f(pb[k]);
  float* od = out + (size_t)t * TD + lane * 8;
  *reinterpret_cast<float4*>(od) = make_float4(o[0], o[1], o[2], o[3]);
  *reinterpret_cast<float4*>(od + 4) = make_float4(o[4], o[5], o[6], o[7]);
}

extern "C" void kernel_launch(void* const* d_in, const int* in_sizes, int n_in,
                              void* d_out, int out_size, void* d_ws, size_t ws_size,
                              hipStream_t stream) {
  const float* x  = (const float*)d_in[0];
  const float* rw = (const float*)d_in[1];
  const float* rb = (const float*)d_in[2];
  const float* w1 = (const float*)d_in[3];
  const float* b1 = (const float*)d_in[4];
  const float* w2 = (const float*)d_in[5];
  const float* b2 = (const float*)d_in[6];
  float* out = (float*)d_out;

  char* w = (char*)d_ws;
  u16* xb    = (u16*)w;           w += (size_t)NT * TD * 2;           // 8 MB
  u16* w1t   = (u16*)w;           w += (size_t)NE * TD * TF * 2;      // 16 MB
  u16* w2t   = (u16*)w;           w += (size_t)NE * TF * TD * 2;      // 16 MB
  u16* H     = (u16*)w;           w += (size_t)CAP * TF * 2;          // 68 MB
  u16* eout  = (u16*)w;           w += (size_t)CAP * TD * 2;          // 17 MB
  int* tok   = (int*)w;           w += (size_t)CAP * 4;
  int* slotOf = (int*)w;          w += (size_t)NT * 2 * 4;
  int2* tokE = (int2*)w;          w += (size_t)NT * 8;
  float2* tokG = (float2*)w;      w += (size_t)NT * 8;
  int* ghist = (int*)w;           w += 256;
  int* cursors = (int*)w;         w += 1024;
  int* offs  = (int*)w;           w += 256;
  int* cnt   = (int*)w;           w += 256;

  // 1. prep: router + x->bf16 + both weight transposes (fused)
  prep_kernel<<<dim3(NT / 4 + 4096), dim3(256), 0, stream>>>(
      x, rw, rb, tokE, tokG, xb, w1, w1t, w2, w2t, ghist);
  // 2. parallel histogram + offsets/cursors (last-block-done)
  hist_kernel<<<dim3(32), dim3(256), 0, stream>>>(tokE, ghist, offs, cnt, cursors);
  // 3. scatter assignments (wave-aggregated) + inverse map
  scatter_kernel<<<dim3(NT / 256), dim3(256), 0, stream>>>(tokE, offs, cursors, tok, slotOf);
  // 4. GEMM1 (A in LDS, B direct-from-global reg-double-buffered)
  gemm1_kernel<<<dim3(CAP / 128, TF / 128), dim3(256), 0, stream>>>(xb, w1t, b1, tok, offs, cnt, H);
  // 5. GEMM2 (same structure)
  gemm2_kernel<<<dim3(CAP / 128, TD / 128), dim3(256), 0, stream>>>(H, w2t, b2, offs, eout);
  // 6. combine (gather + weighted sum)
  combine_kernel<<<dim3(NT / 4), dim3(256), 0, stream>>>(eout, slotOf, tokG, out);
}

// Round 8
// 265.723 us; speedup vs baseline: 1.3457x; 1.3457x over previous
//
#include <hip/hip_runtime.h>
#include <cstdint>
#include <cstddef>

// Problem constants
#define TD 512     // d_model
#define TF 2048    // d_ff
#define NE 8       // experts
#define NT 8192    // tokens (B*S)
#define CAP 17408  // padded assignment slots: 16384 + 8*128

using u16 = unsigned short;
using u32 = unsigned int;

typedef __attribute__((ext_vector_type(8))) __bf16 bf16x8;
typedef __attribute__((ext_vector_type(4))) float f32x4;

__device__ __forceinline__ u16 f2bf(float f) {
  u32 u = __float_as_uint(f);
  u32 r = (u + 0x7fffu + ((u >> 16) & 1u)) >> 16;
  return (u16)r;
}

__device__ __forceinline__ float bf2f(u16 b) {
  return __uint_as_float((u32)b << 16);
}

// async global->LDS, 16B per lane; LDS dest = wave-uniform base + lane*16
__device__ __forceinline__ void load_lds16(const void* g, void* l) {
  __builtin_amdgcn_global_load_lds(
      (const __attribute__((address_space(1))) void*)g,
      (__attribute__((address_space(3))) void*)l, 16, 0, 0);
}

// ---------------- 64x64 transpose+convert tile (256 threads) ----------------
__device__ __forceinline__ void transpose64(const float* __restrict__ ib,
                                            u16* __restrict__ ob, int R, int C,
                                            int r0, int c0, u16* tile /*64*68*/) {
  const int tid = threadIdx.x;
  const int l16 = tid & 15;
  const int grp = tid >> 4;   // 0..15
  #pragma unroll
  for (int p = 0; p < 4; p++) {
    int r = p * 16 + grp;
    float4 v = *reinterpret_cast<const float4*>(ib + (size_t)(r0 + r) * C + c0 + l16 * 4);
    u16 o[4] = {f2bf(v.x), f2bf(v.y), f2bf(v.z), f2bf(v.w)};
    *reinterpret_cast<uint2*>(&tile[r * 68 + l16 * 4]) = *reinterpret_cast<uint2*>(o);
  }
  __syncthreads();
  #pragma unroll
  for (int p = 0; p < 4; p++) {
    int c = p * 16 + grp;
    int rr = l16 * 4;
    u16 o[4] = {tile[(rr + 0) * 68 + c], tile[(rr + 1) * 68 + c],
                tile[(rr + 2) * 68 + c], tile[(rr + 3) * 68 + c]};
    *reinterpret_cast<uint2*>(ob + (size_t)(c0 + c) * R + r0 + rr) = *reinterpret_cast<uint2*>(o);
  }
}

// ---------------- prep: router (+x->bf16) fused with both weight transposes ----------------
__global__ void prep_kernel(const float* __restrict__ x, const float* __restrict__ rw,
                            const float* __restrict__ rb, int2* __restrict__ tokE,
                            float2* __restrict__ tokG, u16* __restrict__ xb,
                            const float* __restrict__ w1, u16* __restrict__ w1t,
                            const float* __restrict__ w2, u16* __restrict__ w2t,
                            int* __restrict__ ghist) {
  __shared__ u16 tile[64 * 68];
  int b = blockIdx.x;
  if (b < NT / 4) {
    if (b == 0 && threadIdx.x < 16) ghist[threadIdx.x] = 0;
    int wv = threadIdx.x >> 6;
    int lane = threadIdx.x & 63;
    int t = b * 4 + wv;
    const float* xr = x + (size_t)t * TD;
    float4 a0 = *reinterpret_cast<const float4*>(xr + lane * 4);
    float4 a1 = *reinterpret_cast<const float4*>(xr + 256 + lane * 4);
    {
      u16 o[8];
      o[0] = f2bf(a0.x); o[1] = f2bf(a0.y); o[2] = f2bf(a0.z); o[3] = f2bf(a0.w);
      o[4] = f2bf(a1.x); o[5] = f2bf(a1.y); o[6] = f2bf(a1.z); o[7] = f2bf(a1.w);
      u16* xo = xb + (size_t)t * TD;
      *reinterpret_cast<uint2*>(xo + lane * 4) = *reinterpret_cast<uint2*>(o);
      *reinterpret_cast<uint2*>(xo + 256 + lane * 4) = *reinterpret_cast<uint2*>(o + 4);
    }
    float p[NE];
    #pragma unroll
    for (int e = 0; e < NE; e++) p[e] = 0.f;
    float av[8] = {a0.x, a0.y, a0.z, a0.w, a1.x, a1.y, a1.z, a1.w};
    #pragma unroll
    for (int j = 0; j < 8; j++) {
      int d = (j < 4) ? (lane * 4 + j) : (256 + lane * 4 + j - 4);
      const float* r = rw + (size_t)d * NE;
      #pragma unroll
      for (int e = 0; e < NE; e++) p[e] += av[j] * r[e];
    }
    #pragma unroll
    for (int off = 32; off >= 1; off >>= 1) {
      #pragma unroll
      for (int e = 0; e < NE; e++) p[e] += __shfl_xor(p[e], off);
    }
    if (lane == 0) {
      float l[NE];
      #pragma unroll
      for (int e = 0; e < NE; e++) l[e] = p[e] + rb[e];
      float m = l[0];
      #pragma unroll
      for (int e = 1; e < NE; e++) m = fmaxf(m, l[e]);
      float g[NE];
      #pragma unroll
      for (int e = 0; e < NE; e++) g[e] = __expf(l[e] - m);
      int i0 = 0;
      #pragma unroll
      for (int e = 1; e < NE; e++) if (g[e] > g[i0]) i0 = e;
      int i1 = -1;
      #pragma unroll
      for (int e = 0; e < NE; e++) {
        if (e == i0) continue;
        if (i1 < 0 || g[e] > g[i1]) i1 = e;
      }
      float inv = 1.f / (g[i0] + g[i1]);
      tokE[t] = make_int2(i0, i1);
      tokG[t] = make_float2(g[i0] * inv, g[i1] * inv);
    }
  } else {
    int tb = b - NT / 4;
    int which = tb >> 11;
    int idx = tb & 2047;
    int e = idx >> 8;
    int tl = idx & 255;
    if (which == 0) {
      int rt = tl >> 5, ct = tl & 31;
      transpose64(w1 + (size_t)e * TD * TF, w1t + (size_t)e * TD * TF,
                  TD, TF, rt * 64, ct * 64, tile);
    } else {
      int rt = tl >> 3, ct = tl & 7;
      transpose64(w2 + (size_t)e * TF * TD, w2t + (size_t)e * TF * TD,
                  TF, TD, rt * 64, ct * 64, tile);
    }
  }
}

// ---------------- hist: parallel histogram + last-block offsets/cursors ----------------
__global__ void hist_kernel(const int2* __restrict__ tokE, int* __restrict__ ghist,
                            int* __restrict__ offs, int* __restrict__ cnt,
                            int* __restrict__ cursors) {
  __shared__ int h[NE];
  __shared__ int last;
  if (threadIdx.x < NE) h[threadIdx.x] = 0;
  __syncthreads();
  int t = blockIdx.x * 256 + threadIdx.x;
  int2 e = tokE[t];
  atomicAdd(&h[e.x], 1);
  atomicAdd(&h[e.y], 1);
  __syncthreads();
  if (threadIdx.x < NE) atomicAdd(&ghist[threadIdx.x], h[threadIdx.x]);
  __threadfence();
  if (threadIdx.x == 0) last = (atomicAdd(&ghist[15], 1) == 31);
  __syncthreads();
  if (last) {
    if (threadIdx.x == 0) {
      int tot = 0;
      for (int i = 0; i < NE; i++) {
        int hv = atomicAdd(&ghist[i], 0);
        offs[i] = tot;
        cnt[i] = hv;
        tot += (hv + 127) & ~127;
      }
      offs[NE] = tot;
    }
    if (threadIdx.x < NE) cursors[threadIdx.x * 16] = 0;
  }
}

// ---------------- scatter assignments (wave-aggregated atomics) ----------------
__global__ void scatter_kernel(const int2* __restrict__ tokE,
                               const int* __restrict__ offs, int* __restrict__ cursors,
                               int* __restrict__ tok, int* __restrict__ slotOf) {
  int t = blockIdx.x * 256 + threadIdx.x;
  int lane = threadIdx.x & 63;
  int2 e = tokE[t];
  #pragma unroll
  for (int k = 0; k < 2; k++) {
    int ek = k ? e.y : e.x;
    #pragma unroll
    for (int ex = 0; ex < NE; ex++) {
      unsigned long long mask = __ballot(ek == ex);
      if (ek == ex) {
        int leader = __ffsll(mask) - 1;
        int rank = __popcll(mask & ((1ull << lane) - 1ull));
        int base = 0;
        if (lane == leader) base = atomicAdd(&cursors[ex * 16], __popcll(mask));
        base = __shfl(base, leader);
        int s = offs[ex] + base + rank;
        tok[s] = t;
        slotOf[t * 2 + k] = s;
      }
    }
  }
}

// ---------------- GEMM1  H = relu(x_gather @ W1 + b1), bf16 out ----------------
// grid (CAP/128, TF/256): each block does 128 slots x 2 f-tiles of 128 —
// A staged once in LDS serves both f-tiles (halves A staging + xb re-fetch).
// XOR-swizzled LDS, async global_load_lds staging (R6 layout).
__global__ __launch_bounds__(256, 2) void gemm1_kernel(
    const u16* __restrict__ xb, const u16* __restrict__ w1t,
    const float* __restrict__ b1, const int* __restrict__ tok,
    const int* __restrict__ offs, const int* __restrict__ cnt,
    u16* __restrict__ H) {
  __shared__ u16 As[128 * 64];
  __shared__ u16 Bs[2][128 * 64];
  __shared__ int tokS[128];
  const int tid = threadIdx.x;
  const int s0 = blockIdx.x * 128;
  const int f0 = blockIdx.y * 256;
  int e = 0;
  #pragma unroll
  for (int i = 1; i <= 7; i++)
    if (s0 >= offs[i]) e = i;
  const int vend = offs[e] + cnt[e];
  if (tid < 128) {
    int s = s0 + tid;
    tokS[tid] = (s < vend) ? tok[s] : 0;
  }
  __syncthreads();

  const int lane = tid & 63;
  const int wv = tid >> 6;
  const int srow = lane >> 3;
  const int scol = (((lane & 7) ^ srow) & 7) * 8;   // swizzled 16B col group
  const int wm = (wv >> 1) * 64;
  const int wn = (wv & 1) * 64;
  const int mrow = lane & 15;
  const int quad = lane >> 4;
  const int rq = mrow & 7;

  f32x4 zero = {0.f, 0.f, 0.f, 0.f};
  f32x4 acc[2][4][4];
  #pragma unroll
  for (int ft = 0; ft < 2; ft++)
    #pragma unroll
    for (int i = 0; i < 4; i++)
      #pragma unroll
      for (int j = 0; j < 4; j++) acc[ft][i][j] = zero;

  const u16* bbase = w1t + ((size_t)e * TF + f0) * TD;

  for (int k0 = 0; k0 < TD; k0 += 64) {
    if (k0) __syncthreads();
    #pragma unroll
    for (int p = 0; p < 4; p++) {
      int row = wv * 32 + p * 8 + srow;
      load_lds16(xb + (size_t)tokS[row] * TD + k0 + scol, &As[(wv * 32 + p * 8) * 64]);
    }
    #pragma unroll
    for (int ft = 0; ft < 2; ft++) {
      #pragma unroll
      for (int p = 0; p < 4; p++) {
        int row = wv * 32 + p * 8 + srow;   // row within f-tile ft
        load_lds16(bbase + (size_t)(ft * 128 + row) * TD + k0 + scol,
                   &Bs[ft][(wv * 32 + p * 8) * 64]);
      }
    }
    __syncthreads();
    #pragma unroll
    for (int ks = 0; ks < 2; ks++) {
      bf16x8 a[4];
      #pragma unroll
      for (int i = 0; i < 4; i++)
        a[i] = *reinterpret_cast<const bf16x8*>(
            &As[(wm + i * 16 + mrow) * 64 + ((ks * 4 + quad) ^ rq) * 8]);
      #pragma unroll
      for (int ft = 0; ft < 2; ft++) {
        bf16x8 b[4];
        #pragma unroll
        for (int j = 0; j < 4; j++)
          b[j] = *reinterpret_cast<const bf16x8*>(
              &Bs[ft][(wn + j * 16 + mrow) * 64 + ((ks * 4 + quad) ^ rq) * 8]);
        #pragma unroll
        for (int i = 0; i < 4; i++)
          #pragma unroll
          for (int j = 0; j < 4; j++)
            acc[ft][i][j] = __builtin_amdgcn_mfma_f32_16x16x32_bf16(a[i], b[j], acc[ft][i][j], 0, 0, 0);
      }
    }
  }

  #pragma unroll
  for (int ft = 0; ft < 2; ft++) {
    float bv[4];
    #pragma unroll
    for (int j = 0; j < 4; j++) bv[j] = b1[e * TF + f0 + ft * 128 + wn + j * 16 + mrow];
    #pragma unroll
    for (int i = 0; i < 4; i++) {
      #pragma unroll
      for (int r = 0; r < 4; r++) {
        int row = s0 + wm + i * 16 + quad * 4 + r;
        u16* hrow = H + (size_t)row * TF + f0 + ft * 128;
        #pragma unroll
        for (int j = 0; j < 4; j++) {
          float v = acc[ft][i][j][r] + bv[j];
          v = v > 0.f ? v : 0.f;
          hrow[wn + j * 16 + mrow] = f2bf(v);
        }
      }
    }
  }
}

// ---------------- GEMM2  eout[slot] = H[slot] @ W2 + b2  (R6 structure) ----------------
// grid (CAP/128, TD/128), block 256
__global__ __launch_bounds__(256, 3) void gemm2_kernel(
    const u16* __restrict__ H, const u16* __restrict__ w2t,
    const float* __restrict__ b2, const int* __restrict__ offs,
    u16* __restrict__ eout) {
  __shared__ u16 As[128 * 64];
  __shared__ u16 Bs[128 * 64];
  const int tid = threadIdx.x;
  const int s0 = blockIdx.x * 128;
  const int d0 = blockIdx.y * 128;
  int e = 0;
  #pragma unroll
  for (int i = 1; i <= 7; i++)
    if (s0 >= offs[i]) e = i;

  const int lane = tid & 63;
  const int wv = tid >> 6;
  const int srow = lane >> 3;
  const int scol = (((lane & 7) ^ srow) & 7) * 8;
  const int wm = (wv >> 1) * 64;
  const int wn = (wv & 1) * 64;
  const int mrow = lane & 15;
  const int quad = lane >> 4;
  const int rq = mrow & 7;

  f32x4 zero = {0.f, 0.f, 0.f, 0.f};
  f32x4 acc[4][4];
  #pragma unroll
  for (int i = 0; i < 4; i++)
    #pragma unroll
    for (int j = 0; j < 4; j++) acc[i][j] = zero;

  const u16* bbase = w2t + ((size_t)e * TD + d0) * TF;

  for (int k0 = 0; k0 < TF; k0 += 64) {
    if (k0) __syncthreads();
    #pragma unroll
    for (int p = 0; p < 4; p++) {
      int row = wv * 32 + p * 8 + srow;
      load_lds16(H + (size_t)(s0 + row) * TF + k0 + scol, &As[(wv * 32 + p * 8) * 64]);
      load_lds16(bbase + (size_t)row * TF + k0 + scol, &Bs[(wv * 32 + p * 8) * 64]);
    }
    __syncthreads();
    #pragma unroll
    for (int ks = 0; ks < 2; ks++) {
      bf16x8 a[4], b[4];
      #pragma unroll
      for (int i = 0; i < 4; i++)
        a[i] = *reinterpret_cast<const bf16x8*>(
            &As[(wm + i * 16 + mrow) * 64 + ((ks * 4 + quad) ^ rq) * 8]);
      #pragma unroll
      for (int j = 0; j < 4; j++)
        b[j] = *reinterpret_cast<const bf16x8*>(
            &Bs[(wn + j * 16 + mrow) * 64 + ((ks * 4 + quad) ^ rq) * 8]);
      #pragma unroll
      for (int i = 0; i < 4; i++)
        #pragma unroll
        for (int j = 0; j < 4; j++)
          acc[i][j] = __builtin_amdgcn_mfma_f32_16x16x32_bf16(a[i], b[j], acc[i][j], 0, 0, 0);
    }
  }

  float bv[4];
  #pragma unroll
  for (int j = 0; j < 4; j++) bv[j] = b2[e * TD + d0 + wn + j * 16 + mrow];
  #pragma unroll
  for (int i = 0; i < 4; i++) {
    #pragma unroll
    for (int r = 0; r < 4; r++) {
      int row = s0 + wm + i * 16 + quad * 4 + r;
      u16* orow = eout + (size_t)row * TD + d0;
      #pragma unroll
      for (int j = 0; j < 4; j++) {
        orow[wn + j * 16 + mrow] = f2bf(acc[i][j][r] + bv[j]);
      }
    }
  }
}

// ---------------- combine: out[t] = gA*eout[sA] + gB*eout[sB] ----------------
__global__ void combine_kernel(const u16* __restrict__ eout, const int* __restrict__ slotOf,
                               const float2* __restrict__ tokG, float* __restrict__ out) {
  int wv = threadIdx.x >> 6;
  int lane = threadIdx.x & 63;
  int t = blockIdx.x * 4 + wv;
  int sA = slotOf[t * 2];
  int sB = slotOf[t * 2 + 1];
  float2 g = tokG[t];
  uint4 ua = *reinterpret_cast<const uint4*>(eout + (size_t)sA * TD + lane * 8);
  uint4 ub = *reinterpret_cast<const uint4*>(eout + (size_t)sB * TD + lane * 8);
  const u16* pa = reinterpret_cast<const u16*>(&ua);
  const u16* pb = reinterpret_cast<const u16*>(&ub);
  float o[8];
  #pragma unroll
  for (int k = 0; k < 8; k++) o[k] = g.x * bf2f(pa[k]) + g.y * bf2f(pb[k]);
  float* od = out + (size_t)t * TD + lane * 8;
  *reinterpret_cast<float4*>(od) = make_float4(o[0], o[1], o[2], o[3]);
  *reinterpret_cast<float4*>(od + 4) = make_float4(o[4], o[5], o[6], o[7]);
}

extern "C" void kernel_launch(void* const* d_in, const int* in_sizes, int n_in,
                              void* d_out, int out_size, void* d_ws, size_t ws_size,
                              hipStream_t stream) {
  const float* x  = (const float*)d_in[0];
  const float* rw = (const float*)d_in[1];
  const float* rb = (const float*)d_in[2];
  const float* w1 = (const float*)d_in[3];
  const float* b1 = (const float*)d_in[4];
  const float* w2 = (const float*)d_in[5];
  const float* b2 = (const float*)d_in[6];
  float* out = (float*)d_out;

  char* w = (char*)d_ws;
  u16* xb    = (u16*)w;           w += (size_t)NT * TD * 2;           // 8 MB
  u16* w1t   = (u16*)w;           w += (size_t)NE * TD * TF * 2;      // 16 MB
  u16* w2t   = (u16*)w;           w += (size_t)NE * TF * TD * 2;      // 16 MB
  u16* H     = (u16*)w;           w += (size_t)CAP * TF * 2;          // 68 MB
  u16* eout  = (u16*)w;           w += (size_t)CAP * TD * 2;          // 17 MB
  int* tok   = (int*)w;           w += (size_t)CAP * 4;
  int* slotOf = (int*)w;          w += (size_t)NT * 2 * 4;
  int2* tokE = (int2*)w;          w += (size_t)NT * 8;
  float2* tokG = (float2*)w;      w += (size_t)NT * 8;
  int* ghist = (int*)w;           w += 256;
  int* cursors = (int*)w;         w += 1024;
  int* offs  = (int*)w;           w += 256;
  int* cnt   = (int*)w;           w += 256;

  // 1. prep: router + x->bf16 + both weight transposes (fused)
  prep_kernel<<<dim3(NT / 4 + 4096), dim3(256), 0, stream>>>(
      x, rw, rb, tokE, tokG, xb, w1, w1t, w2, w2t, ghist);
  // 2. parallel histogram + offsets/cursors (last-block-done)
  hist_kernel<<<dim3(32), dim3(256), 0, stream>>>(tokE, ghist, offs, cnt, cursors);
  // 3. scatter assignments (wave-aggregated) + inverse map
  scatter_kernel<<<dim3(NT / 256), dim3(256), 0, stream>>>(tokE, offs, cursors, tok, slotOf);
  // 4. GEMM1 (2 f-tiles per block, A staged once)
  gemm1_kernel<<<dim3(CAP / 128, TF / 256), dim3(256), 0, stream>>>(xb, w1t, b1, tok, offs, cnt, H);
  // 5. GEMM2 (R6 structure)
  gemm2_kernel<<<dim3(CAP / 128, TD / 128), dim3(256), 0, stream>>>(H, w2t, b2, offs, eout);
  // 6. combine (gather + weighted sum)
  combine_kernel<<<dim3(NT / 4), dim3(256), 0, stream>>>(eout, slotOf, tokG, out);
}